// Round 1
// 1012.592 us; speedup vs baseline: 1.0612x; 1.0612x over previous
//
#include <hip/hip_runtime.h>
#include <math.h>

#define NB 8
#define NH 16
#define NS 1024
#define ND 128

#define BN 32              // keys per K/V tile
#define NT (NS / BN)       // 32 tiles
#define TILE_SH (BN * ND)  // 4096 shorts per tile image (8 KiB)
#define PSTR 40            // Ps row stride in shorts (80 B: conflict-free, 16B-aligned)

typedef float    f32x4 __attribute__((ext_vector_type(4)));
typedef _Float16 f16x8 __attribute__((ext_vector_type(8)));
typedef _Float16 f16x4 __attribute__((ext_vector_type(4)));

#define MFMAH(a, b, c) __builtin_amdgcn_mfma_f32_16x16x32_f16(a, b, c, 0, 0, 0)

// async 16B global->LDS (wave-uniform base + lane*16; images are pre-swizzled in
// global memory so the contiguous landing IS the swizzled tile)
__device__ __forceinline__ void gload16(const void* g, void* l) {
  __builtin_amdgcn_global_load_lds(
      (const __attribute__((address_space(1))) void*)g,
      (__attribute__((address_space(3))) void*)l, 16, 0, 0);
}

// ---------------- fused pre-pass ----------------
// x in [0,8192):      E = scale * rsqrt(scale[0])  fp32 -> fp16   (512R -> 256W MiB)
// x in [8192,12288):  K fp32 -> fp16 image, 32-key tiles, chunk g ^= key&15
// x in [12288,16384): V fp32 -> V^T fp16 image, 32-key tiles, chunk g ^= (d>>1)&3
__global__ void prep_all(const float* __restrict__ scale, _Float16* __restrict__ E,
                         const float* __restrict__ K, short* __restrict__ Kimg,
                         const float* __restrict__ V, short* __restrict__ Vimg,
                         int base) {
  __shared__ _Float16 tbuf[BN * 132];
  const int x = blockIdx.x + base;
  const int tid = threadIdx.x;
  if (x < 8192) {
    const size_t i0 = ((size_t)x * 256 + tid) * 8;  // within H*S*S = 2^24
    float4 a0 = *(const float4*)(scale + i0);
    float4 b0 = *(const float4*)(scale + i0 + 4);
    float r[8] = {rsqrtf(a0.x), rsqrtf(a0.y), rsqrtf(a0.z), rsqrtf(a0.w),
                  rsqrtf(b0.x), rsqrtf(b0.y), rsqrtf(b0.z), rsqrtf(b0.w)};
    // b = 0 reuses the already-loaded scale[0] values (saves a 64 MiB re-read)
    *(f16x8*)(E + i0) =
        (f16x8){(_Float16)(a0.x * r[0]), (_Float16)(a0.y * r[1]),
                (_Float16)(a0.z * r[2]), (_Float16)(a0.w * r[3]),
                (_Float16)(b0.x * r[4]), (_Float16)(b0.y * r[5]),
                (_Float16)(b0.z * r[6]), (_Float16)(b0.w * r[7])};
#pragma unroll
    for (int b = 1; b < NB; ++b) {
      const float* sp = scale + ((size_t)b << 24) + i0;
      float4 a = *(const float4*)sp;
      float4 bb = *(const float4*)(sp + 4);
      *(f16x8*)(E + ((size_t)b << 24) + i0) =
          (f16x8){(_Float16)(a.x * r[0]),  (_Float16)(a.y * r[1]),
                  (_Float16)(a.z * r[2]),  (_Float16)(a.w * r[3]),
                  (_Float16)(bb.x * r[4]), (_Float16)(bb.y * r[5]),
                  (_Float16)(bb.z * r[6]), (_Float16)(bb.w * r[7])};
    }
  } else if (x < 12288) {
    const int p = x - 8192;
    const int t = p & 31, bh = p >> 5;
    const float* Kt = K + ((size_t)bh * NS + t * BN) * ND;
    short* img = Kimg + ((size_t)bh * NT + t) * TILE_SH;
#pragma unroll
    for (int i = 0; i < 4; ++i) {
      int f = tid + i * 256;  // 0..1023 float4 units
      int key = f >> 5, d4 = (f & 31) << 2;
      float4 v = *(const float4*)(Kt + (size_t)key * ND + d4);
      f16x4 hv = {(_Float16)v.x, (_Float16)v.y, (_Float16)v.z, (_Float16)v.w};
      int gp = (d4 >> 3) ^ (key & 15);
      *(f16x4*)(img + key * 128 + gp * 8 + (d4 & 7)) = hv;
    }
  } else {
    const int p = x - 12288;
    const int t = p & 31, bh = p >> 5;
    const float* Vt = V + ((size_t)bh * NS + t * BN) * ND;
#pragma unroll
    for (int i = 0; i < 4; ++i) {
      int f = tid + i * 256;
      int key = f >> 5, d4 = (f & 31) << 2;
      float4 v = *(const float4*)(Vt + (size_t)key * ND + d4);
      *(f16x4*)&tbuf[key * 132 + d4] =
          (f16x4){(_Float16)v.x, (_Float16)v.y, (_Float16)v.z, (_Float16)v.w};
    }
    __syncthreads();
    short* img = Vimg + ((size_t)bh * NT + t) * TILE_SH;
#pragma unroll
    for (int i = 0; i < 2; ++i) {
      int u = tid + i * 256;  // 0..511 f16x8 units
      int d = u >> 2, k8 = u & 3;
      f16x8 o;
#pragma unroll
      for (int e = 0; e < 8; ++e) o[e] = tbuf[(k8 * 8 + e) * 132 + d];
      *(f16x8*)(img + d * BN + ((k8 ^ ((d >> 1) & 3)) * 8)) = o;
    }
  }
}

// ---------------- main fp16 MFMA flash-attention ----------------
// 256 thr = 4 waves; BM=128 (32 q/wave), BN=32 keys/tile, double-buffered K/V LDS.
// One __syncthreads per tile; all VMEM for tile t+1 is issued a full compute phase
// before the barrier whose vmcnt(0)-drain waits on it -> latency hidden.
// LDS = 16K (Ks x2) + 16K (Vs x2) + 10K (Ps) = 42 KiB -> 3 blocks/CU.

#define ISSUE(T, B)                                              \
  do {                                                           \
    const short* kg_ = Kb + (T) * TILE_SH + tid * 8;             \
    const short* vg_ = Vb + (T) * TILE_SH + tid * 8;             \
    gload16(kg_, &Ks[B][tid * 8]);                               \
    gload16(kg_ + 2048, &Ks[B][tid * 8 + 2048]);                 \
    gload16(vg_, &Vs[B][tid * 8]);                               \
    gload16(vg_ + 2048, &Vs[B][tid * 8 + 2048]);                 \
  } while (0)

#define LOADE(DST, T)                                                             \
  do {                                                                            \
    _Pragma("unroll") for (int nf = 0; nf < 2; ++nf)                              \
        _Pragma("unroll") for (int m0 = 0; m0 < 2; ++m0)                          \
            DST[nf][m0] = *(const f16x4*)(Eb + (size_t)(q0 + nf * 16 + c) * NS +  \
                                          (T) * BN + m0 * 16 + quad * 4);         \
  } while (0)

#define LOADS(SV, S0, T)                                                          \
  do {                                                                            \
    _Pragma("unroll") for (int nf = 0; nf < 2; ++nf)                              \
        _Pragma("unroll") for (int m0 = 0; m0 < 2; ++m0) {                        \
      size_t off_ = (size_t)(q0 + nf * 16 + c) * NS + (T) * BN + m0 * 16 + quad * 4; \
      SV[nf][m0] = *(const f32x4*)(sclb + off_);                                  \
      S0[nf][m0] = *(const f32x4*)(sc0b + off_);                                  \
    }                                                                             \
  } while (0)

// One 32-key tile: QK^T (transposed: A=K,B=Q -> S^T[key][q]) -> online softmax
// (exact defer-max: skip rescale when no row's max grows) -> PV.
#define TILE_STEP(BUF, EF, SCV, SC0, KT)                                             \
  do {                                                                               \
    f32x4 S_[2][2];                                                                  \
    _Pragma("unroll") for (int nf = 0; nf < 2; ++nf)                                 \
        _Pragma("unroll") for (int m0 = 0; m0 < 2; ++m0)                             \
            S_[nf][m0] = (f32x4){0.f, 0.f, 0.f, 0.f};                                \
    _Pragma("unroll") for (int m0 = 0; m0 < 2; ++m0) {                               \
      _Pragma("unroll") for (int kb = 0; kb < 4; ++kb) {                             \
        const f16x8 a_ = *(const f16x8*)&Ks[BUF][(m0 * 16 + c) * 128 +               \
                                                 (((kb << 2) | quad) ^ c) * 8];      \
        S_[0][m0] = MFMAH(a_, qf[0][kb], S_[0][m0]);                                 \
        S_[1][m0] = MFMAH(a_, qf[1][kb], S_[1][m0]);                                 \
      }                                                                              \
    }                                                                                \
    float al2_[2];                                                                   \
    int skipall_ = 1;                                                                \
    _Pragma("unroll") for (int nf = 0; nf < 2; ++nf) {                               \
      float sv[8];                                                                   \
      _Pragma("unroll") for (int m0 = 0; m0 < 2; ++m0)                               \
          _Pragma("unroll") for (int r = 0; r < 4; ++r) {                            \
        float e_ = USE_E ? (float)EF[nf][m0][r]                                      \
                         : SCV[nf][m0][r] * rsqrtf(SC0[nf][m0][r]);                  \
        sv[m0 * 4 + r] = S_[nf][m0][r] * e_;                                         \
      }                                                                              \
      float tm = sv[0];                                                              \
      _Pragma("unroll") for (int i = 1; i < 8; ++i) tm = fmaxf(tm, sv[i]);           \
      tm = fmaxf(tm, __shfl_xor(tm, 16));                                            \
      tm = fmaxf(tm, __shfl_xor(tm, 32));                                            \
      float mn, al;                                                                  \
      if (__all(tm <= m_[nf])) { /* exact: al = exp(0) = 1 */                        \
        mn = m_[nf]; al = 1.f;                                                       \
      } else {                                                                       \
        mn = fmaxf(m_[nf], tm);                                                      \
        al = __expf(m_[nf] - mn);                                                    \
        m_[nf] = mn;                                                                 \
        skipall_ = 0;                                                                \
      }                                                                              \
      al2_[nf] = al;                                                                 \
      float ps = 0.f;                                                                \
      _Float16 pb[8];                                                                \
      _Pragma("unroll") for (int i = 0; i < 8; ++i) {                                \
        float p_ = __expf(sv[i] - mn);                                               \
        ps += p_;                                                                    \
        pb[i] = (_Float16)p_;                                                        \
      }                                                                              \
      ps += __shfl_xor(ps, 16);                                                      \
      ps += __shfl_xor(ps, 32);                                                      \
      ls_[nf] = ls_[nf] * al + ps;                                                   \
      _Float16* pr_ = &Ps[(size_t)(w * 32 + nf * 16 + c) * PSTR];                    \
      *(f16x4*)(pr_ + quad * 4)      = (f16x4){pb[0], pb[1], pb[2], pb[3]};          \
      *(f16x4*)(pr_ + 16 + quad * 4) = (f16x4){pb[4], pb[5], pb[6], pb[7]};          \
    }                                                                                \
    if (!skipall_) {                                                                 \
      _Pragma("unroll") for (int pf = 0; pf < 2; ++pf) {                             \
        float ar_[4];                                                                \
        _Pragma("unroll") for (int r = 0; r < 4; ++r)                                \
            ar_[r] = __shfl(al2_[pf], quad * 4 + r);                                 \
        _Pragma("unroll") for (int n0 = 0; n0 < 8; ++n0)                             \
            _Pragma("unroll") for (int r = 0; r < 4; ++r) O[pf][n0][r] *= ar_[r];    \
      }                                                                              \
    }                                                                                \
    const f16x8 pf0_ = *(const f16x8*)&Ps[(size_t)(w * 32 + c) * PSTR + quad * 8];   \
    const f16x8 pf1_ =                                                               \
        *(const f16x8*)&Ps[(size_t)(w * 32 + 16 + c) * PSTR + quad * 8];             \
    _Pragma("unroll") for (int n0 = 0; n0 < 8; ++n0) {                               \
      const f16x8 b_ = *(const f16x8*)&Vs[BUF][(n0 * 16 + c) * 32 +                  \
                                              (quad ^ ((c >> 1) & 3)) * 8];          \
      O[0][n0] = MFMAH(pf0_, b_, O[0][n0]);                                          \
      O[1][n0] = MFMAH(pf1_, b_, O[1][n0]);                                          \
    }                                                                                \
  } while (0)

template <bool USE_E>
__launch_bounds__(256, 3)
__global__ void attn_f16(const float* __restrict__ Q, const short* __restrict__ Kimg,
                         const short* __restrict__ Vimg, const _Float16* __restrict__ E,
                         const float* __restrict__ scale, float* __restrict__ out) {
  __shared__ short Ks[2][TILE_SH];     // 2 x 8 KiB [key][d] swizzled
  __shared__ short Vs[2][TILE_SH];     // 2 x 8 KiB [d][key] swizzled
  __shared__ _Float16 Ps[128 * PSTR];  // 10 KiB   [q][key]

  const int tid = threadIdx.x;
  const int w = tid >> 6, l = tid & 63;
  const int quad = l >> 4, c = l & 15;

  // XCD swizzle: all 8 q-blocks of one (b,h) -> same XCD; K/V tiles L2-hit.
  const int x = blockIdx.x;
  const int bh = ((x >> 6) << 3) | (x & 7);
  const int qblk = (x >> 3) & 7;
  const int q0 = qblk * 128 + w * 32;

  const short* Kb = Kimg + (size_t)bh * (NT * TILE_SH);
  const short* Vb = Vimg + (size_t)bh * (NT * TILE_SH);
  const _Float16* Eb = E + ((size_t)bh << 20);
  const float* sclb = scale + ((size_t)bh << 20);
  const float* sc0b = scale + ((size_t)(bh & 15) << 20);

  // prologue: get tile 0 + its E in flight before anything else
  ISSUE(0, 0);
  f16x4 efA[2][2], efB[2][2];
  if (USE_E) LOADE(efA, 0);

  // Q B-fragments fp32->fp16: lane holds Q[q0+nf*16+c][kb*32+quad*8+j]
  f16x8 qf[2][4];
  {
    const float* Qb = Q + ((size_t)bh * NS + q0) * ND;
#pragma unroll
    for (int nf = 0; nf < 2; ++nf)
#pragma unroll
      for (int kb = 0; kb < 4; ++kb) {
        const float* p = Qb + (size_t)(nf * 16 + c) * ND + kb * 32 + quad * 8;
        float4 a = *(const float4*)p;
        float4 b = *(const float4*)(p + 4);
        qf[nf][kb] = (f16x8){(_Float16)a.x, (_Float16)a.y, (_Float16)a.z, (_Float16)a.w,
                             (_Float16)b.x, (_Float16)b.y, (_Float16)b.z, (_Float16)b.w};
      }
  }

  float m_[2] = {-INFINITY, -INFINITY}, ls_[2] = {0.f, 0.f};
  f32x4 O[2][8];
#pragma unroll
  for (int pf = 0; pf < 2; ++pf)
#pragma unroll
    for (int n0 = 0; n0 < 8; ++n0) O[pf][n0] = (f32x4){0.f, 0.f, 0.f, 0.f};

  f32x4 sclvA[2][2], sc0vA[2][2], sclvB[2][2], sc0vB[2][2];  // !USE_E only

#pragma unroll 1
  for (int kt = 0; kt < NT; kt += 2) {
    // ---- half A: compute tile kt from buf0; prefetch kt+1 -> buf1 ----
    __syncthreads();  // drains gloads(kt)+E(kt): in flight for a full phase
    if (!USE_E) LOADS(sclvA, sc0vA, kt);  // issued before gloads: waits leave them in flight
    ISSUE(kt + 1, 1);
    if (USE_E) LOADE(efB, kt + 1);
    TILE_STEP(0, efA, sclvA, sc0vA, kt);
    // ---- half B: compute tile kt+1 from buf1; prefetch kt+2 -> buf0 ----
    __syncthreads();
    if (!USE_E) LOADS(sclvB, sc0vB, kt + 1);
    if (kt + 2 < NT) {
      ISSUE(kt + 2, 0);
      if (USE_E) LOADE(efA, kt + 2);
    }
    TILE_STEP(1, efB, sclvB, sc0vB, kt + 1);
  }

  // ---- epilogue ----
  float* ob = out + ((size_t)bh * NS + q0) * ND;
#pragma unroll
  for (int pf = 0; pf < 2; ++pf)
#pragma unroll
    for (int r = 0; r < 4; ++r) {
      float lv = __shfl(ls_[pf], quad * 4 + r);
      float inv = 1.0f / lv;
      int row = pf * 16 + quad * 4 + r;
#pragma unroll
      for (int n0 = 0; n0 < 8; ++n0)
        ob[(size_t)row * ND + n0 * 16 + c] = O[pf][n0][r] * inv;
    }
}

// ---------------- fallback (R1 fp32 kernel, verified) ----------------
#define TQ 16
#define TK 64
#define PITCH 129
__launch_bounds__(256, 2)
__global__ void attn_fp32(const float* __restrict__ Q, const float* __restrict__ K,
                          const float* __restrict__ V, const float* __restrict__ scale,
                          float* __restrict__ out) {
  __shared__ float qs[TQ][ND];
  __shared__ float kv[TK][PITCH];
  __shared__ float ps[4][4][TK];
  const int tid = threadIdx.x;
  const int w = tid >> 6, l = tid & 63;
  const int bid = blockIdx.x;
  const int qt = bid & 63, h = (bid >> 6) & 15, b = bid >> 10;
  const size_t bh = (size_t)b * NH + h;
  const float* Qb = Q + (bh * NS + (size_t)qt * TQ) * ND;
  const float* Kb = K + bh * NS * ND;
  const float* Vb = V + bh * NS * ND;
  {
    const float4* Q4 = (const float4*)Qb;
    float4* qs4 = (float4*)&qs[0][0];
    qs4[tid] = Q4[tid];
    qs4[tid + 256] = Q4[tid + 256];
  }
  const int q0 = qt * TQ + w * 4;
  const float* sc0p[4];
  const float* sclp[4];
#pragma unroll
  for (int i = 0; i < 4; ++i) {
    const int qg = q0 + i;
    sc0p[i] = scale + ((size_t)h * NS + qg) * NS;
    sclp[i] = scale + (bh * NS + qg) * NS;
  }
  float m[4] = {-INFINITY, -INFINITY, -INFINITY, -INFINITY};
  float lsum[4] = {0.f, 0.f, 0.f, 0.f};
  float oa[4] = {0.f, 0.f, 0.f, 0.f};
  float ob[4] = {0.f, 0.f, 0.f, 0.f};
  for (int kt = 0; kt < NS / TK; ++kt) {
    __syncthreads();
    {
      const float4* K4 = (const float4*)(Kb + (size_t)kt * TK * ND);
#pragma unroll
      for (int i = 0; i < 8; ++i) {
        const int f = tid + i * 256;
        const float4 t4 = K4[f];
        const int r = f >> 5, cc = (f & 31) << 2;
        kv[r][cc] = t4.x; kv[r][cc + 1] = t4.y; kv[r][cc + 2] = t4.z; kv[r][cc + 3] = t4.w;
      }
    }
    __syncthreads();
    const int kg = kt * TK + l;
    float sc0[4], scl[4];
#pragma unroll
    for (int i = 0; i < 4; ++i) { sc0[i] = sc0p[i][kg]; scl[i] = sclp[i][kg]; }
    float s[4] = {0.f, 0.f, 0.f, 0.f};
#pragma unroll 8
    for (int d = 0; d < ND; ++d) {
      const float kd = kv[l][d];
      s[0] = fmaf(qs[w * 4 + 0][d], kd, s[0]);
      s[1] = fmaf(qs[w * 4 + 1][d], kd, s[1]);
      s[2] = fmaf(qs[w * 4 + 2][d], kd, s[2]);
      s[3] = fmaf(qs[w * 4 + 3][d], kd, s[3]);
    }
#pragma unroll
    for (int i = 0; i < 4; ++i) {
      const float svv = s[i] * scl[i] * rsqrtf(sc0[i]);
      float mx = svv;
#pragma unroll
      for (int off = 32; off > 0; off >>= 1) mx = fmaxf(mx, __shfl_xor(mx, off));
      const float mn = fmaxf(m[i], mx);
      const float p = __expf(svv - mn);
      const float al = __expf(m[i] - mn);
      float psum = p;
#pragma unroll
      for (int off = 32; off > 0; off >>= 1) psum += __shfl_xor(psum, off);
      lsum[i] = lsum[i] * al + psum;
      m[i] = mn;
      oa[i] *= al;
      ob[i] *= al;
      ps[w][i][l] = p;
    }
    __syncthreads();
    {
      const float4* V4 = (const float4*)(Vb + (size_t)kt * TK * ND);
#pragma unroll
      for (int i = 0; i < 8; ++i) {
        const int f = tid + i * 256;
        const float4 t4 = V4[f];
        const int r = f >> 5, cc = (f & 31) << 2;
        kv[r][cc] = t4.x; kv[r][cc + 1] = t4.y; kv[r][cc + 2] = t4.z; kv[r][cc + 3] = t4.w;
      }
    }
    __syncthreads();
#pragma unroll 4
    for (int k2 = 0; k2 < TK; ++k2) {
      const float v0 = kv[k2][l];
      const float v1 = kv[k2][64 + l];
#pragma unroll
      for (int i = 0; i < 4; ++i) {
        const float p = ps[w][i][k2];
        oa[i] = fmaf(p, v0, oa[i]);
        ob[i] = fmaf(p, v1, ob[i]);
      }
    }
  }
  float* op = out + (bh * NS + q0) * ND;
#pragma unroll
  for (int i = 0; i < 4; ++i) {
    const float inv = 1.0f / lsum[i];
    op[(size_t)i * ND + l] = oa[i] * inv;
    op[(size_t)i * ND + 64 + l] = ob[i] * inv;
  }
}

extern "C" void kernel_launch(void* const* d_in, const int* in_sizes, int n_in,
                              void* d_out, int out_size, void* d_ws, size_t ws_size,
                              hipStream_t stream) {
  const float* Q = (const float*)d_in[0];
  const float* K = (const float*)d_in[1];
  const float* V = (const float*)d_in[2];
  const float* scale = (const float*)d_in[3];
  float* out = (float*)d_out;

  const size_t KV_BYTES = (size_t)NB * NH * NS * ND * 2;  // 32 MiB each
  const size_t E_BYTES = (size_t)NB * NH * NS * NS * 2;   // 256 MiB
  const size_t needB = 2 * KV_BYTES;                      // 64 MiB
  const size_t needA = needB + E_BYTES;                   // 320 MiB

  if (ws_size >= needB) {
    short* Kimg = (short*)d_ws;
    short* Vimg = (short*)((char*)d_ws + KV_BYTES);
    if (ws_size >= needA) {
      _Float16* E = (_Float16*)((char*)d_ws + needB);
      prep_all<<<dim3(16384), dim3(256), 0, stream>>>(scale, E, K, Kimg, V, Vimg, 0);
      attn_f16<true><<<dim3(1024), dim3(256), 0, stream>>>(Q, Kimg, Vimg, E, scale, out);
    } else {
      prep_all<<<dim3(8192), dim3(256), 0, stream>>>(scale, nullptr, K, Kimg, V, Vimg,
                                                     8192);
      attn_f16<false><<<dim3(1024), dim3(256), 0, stream>>>(Q, Kimg, Vimg, nullptr,
                                                            scale, out);
    }
  } else {
    attn_fp32<<<dim3(NB * NH * (NS / TK) * 4), dim3(256), 0, stream>>>(Q, K, V, scale,
                                                                       out);
  }
}

// Round 2
// 922.476 us; speedup vs baseline: 1.1649x; 1.0977x over previous
//
#include <hip/hip_runtime.h>
#include <math.h>

#define NB 8
#define NH 16
#define NS 1024
#define ND 128

#define BN 32              // keys per K/V tile
#define NT (NS / BN)       // 32 tiles
#define TILE_SH (BN * ND)  // 4096 shorts per tile image (8 KiB)
#define PSTR 40            // Ps row stride in shorts (80 B: conflict-free, 16B-aligned)

typedef float    f32x4 __attribute__((ext_vector_type(4)));
typedef _Float16 f16x8 __attribute__((ext_vector_type(8)));
typedef _Float16 f16x4 __attribute__((ext_vector_type(4)));

#define MFMAH(a, b, c) __builtin_amdgcn_mfma_f32_16x16x32_f16(a, b, c, 0, 0, 0)

// async 16B global->LDS (wave-uniform base + lane*16; images are pre-swizzled in
// global memory so the contiguous landing IS the swizzled tile)
__device__ __forceinline__ void gload16(const void* g, void* l) {
  __builtin_amdgcn_global_load_lds(
      (const __attribute__((address_space(1))) void*)g,
      (__attribute__((address_space(3))) void*)l, 16, 0, 0);
}

// ---------------- pre-pass: K/V fp32 -> fp16 swizzled tile images ----------------
// x in [0,4096):     K fp32 -> fp16 image, 32-key tiles, chunk g ^= key&15
// x in [4096,8192):  V fp32 -> V^T fp16 image, 32-key tiles, chunk g ^= (d>>1)&3
__global__ void prep_kv(const float* __restrict__ K, short* __restrict__ Kimg,
                        const float* __restrict__ V, short* __restrict__ Vimg) {
  __shared__ _Float16 tbuf[BN * 132];
  const int x = blockIdx.x;
  const int tid = threadIdx.x;
  if (x < 4096) {
    const int t = x & 31, bh = x >> 5;
    const float* Kt = K + ((size_t)bh * NS + t * BN) * ND;
    short* img = Kimg + ((size_t)bh * NT + t) * TILE_SH;
#pragma unroll
    for (int i = 0; i < 4; ++i) {
      int f = tid + i * 256;  // 0..1023 float4 units
      int key = f >> 5, d4 = (f & 31) << 2;
      float4 v = *(const float4*)(Kt + (size_t)key * ND + d4);
      f16x4 hv = {(_Float16)v.x, (_Float16)v.y, (_Float16)v.z, (_Float16)v.w};
      int gp = (d4 >> 3) ^ (key & 15);
      *(f16x4*)(img + key * 128 + gp * 8 + (d4 & 7)) = hv;
    }
  } else {
    const int p = x - 4096;
    const int t = p & 31, bh = p >> 5;
    const float* Vt = V + ((size_t)bh * NS + t * BN) * ND;
#pragma unroll
    for (int i = 0; i < 4; ++i) {
      int f = tid + i * 256;
      int key = f >> 5, d4 = (f & 31) << 2;
      float4 v = *(const float4*)(Vt + (size_t)key * ND + d4);
      *(f16x4*)&tbuf[key * 132 + d4] =
          (f16x4){(_Float16)v.x, (_Float16)v.y, (_Float16)v.z, (_Float16)v.w};
    }
    __syncthreads();
    short* img = Vimg + ((size_t)bh * NT + t) * TILE_SH;
#pragma unroll
    for (int i = 0; i < 2; ++i) {
      int u = tid + i * 256;  // 0..511 f16x8 units
      int d = u >> 2, k8 = u & 3;
      f16x8 o;
#pragma unroll
      for (int e = 0; e < 8; ++e) o[e] = tbuf[(k8 * 8 + e) * 132 + d];
      *(f16x8*)(img + d * BN + ((k8 ^ ((d >> 1) & 3)) * 8)) = o;
    }
  }
}

// ---------------- main fp16 MFMA flash-attention ----------------
// 256 thr = 4 waves; BM=128 (32 q/wave), BN=32 keys/tile, double-buffered K/V LDS.
// One __syncthreads per tile; all VMEM for tile t+1 (K/V gloads AND the fp32
// scale/scale0 register loads) is issued a full compute phase before the barrier
// that drains it -> latency hidden.
// __launch_bounds__(256,2): VGPR cap 256 (live set ~210) -> NO spills. 2 blocks/CU,
// LDS 42 KiB.

#define ISSUE(T, B)                                              \
  do {                                                           \
    const short* kg_ = Kb + (T) * TILE_SH + tid * 8;             \
    const short* vg_ = Vb + (T) * TILE_SH + tid * 8;             \
    gload16(kg_, &Ks[B][tid * 8]);                               \
    gload16(kg_ + 2048, &Ks[B][tid * 8 + 2048]);                 \
    gload16(vg_, &Vs[B][tid * 8]);                               \
    gload16(vg_ + 2048, &Vs[B][tid * 8 + 2048]);                 \
  } while (0)

#define LOADS(SV, S0, T)                                                             \
  do {                                                                               \
    _Pragma("unroll") for (int nf = 0; nf < 2; ++nf)                                 \
        _Pragma("unroll") for (int m0 = 0; m0 < 2; ++m0) {                           \
      size_t off_ = (size_t)(q0 + nf * 16 + c) * NS + (T) * BN + m0 * 16 + quad * 4; \
      SV[nf][m0] = *(const f32x4*)(sclb + off_);                                     \
      S0[nf][m0] = *(const f32x4*)(sc0b + off_);                                     \
    }                                                                                \
  } while (0)

// One 32-key tile: QK^T (transposed: A=K,B=Q -> S^T[key][q]) -> online softmax
// (exact defer-max: skip rescale when no row's max grows) -> PV.
#define TILE_STEP(BUF, SCV, SC0)                                                     \
  do {                                                                               \
    f32x4 S_[2][2];                                                                  \
    _Pragma("unroll") for (int nf = 0; nf < 2; ++nf)                                 \
        _Pragma("unroll") for (int m0 = 0; m0 < 2; ++m0)                             \
            S_[nf][m0] = (f32x4){0.f, 0.f, 0.f, 0.f};                                \
    _Pragma("unroll") for (int m0 = 0; m0 < 2; ++m0) {                               \
      _Pragma("unroll") for (int kb = 0; kb < 4; ++kb) {                             \
        const f16x8 a_ = *(const f16x8*)&Ks[BUF][(m0 * 16 + c) * 128 +               \
                                                 (((kb << 2) | quad) ^ c) * 8];      \
        S_[0][m0] = MFMAH(a_, qf[0][kb], S_[0][m0]);                                 \
        S_[1][m0] = MFMAH(a_, qf[1][kb], S_[1][m0]);                                 \
      }                                                                              \
    }                                                                                \
    float al2_[2];                                                                   \
    int skipall_ = 1;                                                                \
    _Pragma("unroll") for (int nf = 0; nf < 2; ++nf) {                               \
      float sv[8];                                                                   \
      _Pragma("unroll") for (int m0 = 0; m0 < 2; ++m0)                               \
          _Pragma("unroll") for (int r = 0; r < 4; ++r) {                            \
        float e_ = SCV[nf][m0][r] * rsqrtf(SC0[nf][m0][r]);                          \
        sv[m0 * 4 + r] = S_[nf][m0][r] * e_;                                         \
      }                                                                              \
      float tm = sv[0];                                                              \
      _Pragma("unroll") for (int i = 1; i < 8; ++i) tm = fmaxf(tm, sv[i]);           \
      tm = fmaxf(tm, __shfl_xor(tm, 16));                                            \
      tm = fmaxf(tm, __shfl_xor(tm, 32));                                            \
      float mn, al;                                                                  \
      if (__all(tm <= m_[nf])) { /* exact: al = exp(0) = 1 */                        \
        mn = m_[nf]; al = 1.f;                                                       \
      } else {                                                                       \
        mn = fmaxf(m_[nf], tm);                                                      \
        al = __expf(m_[nf] - mn);                                                    \
        m_[nf] = mn;                                                                 \
        skipall_ = 0;                                                                \
      }                                                                              \
      al2_[nf] = al;                                                                 \
      float ps = 0.f;                                                                \
      _Float16 pb[8];                                                                \
      _Pragma("unroll") for (int i = 0; i < 8; ++i) {                                \
        float p_ = __expf(sv[i] - mn);                                               \
        ps += p_;                                                                    \
        pb[i] = (_Float16)p_;                                                        \
      }                                                                              \
      ps += __shfl_xor(ps, 16);                                                      \
      ps += __shfl_xor(ps, 32);                                                      \
      ls_[nf] = ls_[nf] * al + ps;                                                   \
      _Float16* pr_ = &Ps[(size_t)(w * 32 + nf * 16 + c) * PSTR];                    \
      *(f16x4*)(pr_ + quad * 4)      = (f16x4){pb[0], pb[1], pb[2], pb[3]};          \
      *(f16x4*)(pr_ + 16 + quad * 4) = (f16x4){pb[4], pb[5], pb[6], pb[7]};          \
    }                                                                                \
    if (!skipall_) {                                                                 \
      _Pragma("unroll") for (int pf = 0; pf < 2; ++pf) {                             \
        float ar_[4];                                                                \
        _Pragma("unroll") for (int r = 0; r < 4; ++r)                                \
            ar_[r] = __shfl(al2_[pf], quad * 4 + r);                                 \
        _Pragma("unroll") for (int n0 = 0; n0 < 8; ++n0)                             \
            _Pragma("unroll") for (int r = 0; r < 4; ++r) O[pf][n0][r] *= ar_[r];    \
      }                                                                              \
    }                                                                                \
    const f16x8 pf0_ = *(const f16x8*)&Ps[(size_t)(w * 32 + c) * PSTR + quad * 8];   \
    const f16x8 pf1_ =                                                               \
        *(const f16x8*)&Ps[(size_t)(w * 32 + 16 + c) * PSTR + quad * 8];             \
    _Pragma("unroll") for (int n0 = 0; n0 < 8; ++n0) {                               \
      const f16x8 b_ = *(const f16x8*)&Vs[BUF][(n0 * 16 + c) * 32 +                  \
                                              (quad ^ ((c >> 1) & 3)) * 8];          \
      O[0][n0] = MFMAH(pf0_, b_, O[0][n0]);                                          \
      O[1][n0] = MFMAH(pf1_, b_, O[1][n0]);                                          \
    }                                                                                \
  } while (0)

__launch_bounds__(256, 2)
__global__ void attn_f16(const float* __restrict__ Q, const short* __restrict__ Kimg,
                         const short* __restrict__ Vimg, const float* __restrict__ scale,
                         float* __restrict__ out) {
  __shared__ short Ks[2][TILE_SH];     // 2 x 8 KiB [key][d] swizzled
  __shared__ short Vs[2][TILE_SH];     // 2 x 8 KiB [d][key] swizzled
  __shared__ _Float16 Ps[128 * PSTR];  // 10 KiB   [q][key]

  const int tid = threadIdx.x;
  const int w = tid >> 6, l = tid & 63;
  const int quad = l >> 4, c = l & 15;

  // XCD swizzle: all 8 q-blocks of one (b,h) -> same XCD; K/V tiles (and the
  // shared scale[0] h-slice) L2-hit.
  const int x = blockIdx.x;
  const int bh = ((x >> 6) << 3) | (x & 7);
  const int qblk = (x >> 3) & 7;
  const int q0 = qblk * 128 + w * 32;

  const short* Kb = Kimg + (size_t)bh * (NT * TILE_SH);
  const short* Vb = Vimg + (size_t)bh * (NT * TILE_SH);
  const float* sclb = scale + ((size_t)bh << 20);
  const float* sc0b = scale + ((size_t)(bh & 15) << 20);

  // Q B-fragments fp32->fp16 FIRST (so waiting on them leaves later VMEM in flight)
  f16x8 qf[2][4];
  f32x4 sclvA[2][2], sc0vA[2][2], sclvB[2][2], sc0vB[2][2];
  {
    const float* Qb = Q + ((size_t)bh * NS + q0) * ND;
    float4 qa[2][4][2];
#pragma unroll
    for (int nf = 0; nf < 2; ++nf)
#pragma unroll
      for (int kb = 0; kb < 4; ++kb) {
        const float* p = Qb + (size_t)(nf * 16 + c) * ND + kb * 32 + quad * 8;
        qa[nf][kb][0] = *(const float4*)p;
        qa[nf][kb][1] = *(const float4*)(p + 4);
      }
    // tile-0 prefetch in flight before the conversion waits on Q
    ISSUE(0, 0);
    LOADS(sclvA, sc0vA, 0);
#pragma unroll
    for (int nf = 0; nf < 2; ++nf)
#pragma unroll
      for (int kb = 0; kb < 4; ++kb) {
        float4 a = qa[nf][kb][0], b = qa[nf][kb][1];
        qf[nf][kb] = (f16x8){(_Float16)a.x, (_Float16)a.y, (_Float16)a.z, (_Float16)a.w,
                             (_Float16)b.x, (_Float16)b.y, (_Float16)b.z, (_Float16)b.w};
      }
  }

  float m_[2] = {-INFINITY, -INFINITY}, ls_[2] = {0.f, 0.f};
  f32x4 O[2][8];
#pragma unroll
  for (int pf = 0; pf < 2; ++pf)
#pragma unroll
    for (int n0 = 0; n0 < 8; ++n0) O[pf][n0] = (f32x4){0.f, 0.f, 0.f, 0.f};

#pragma unroll 1
  for (int kt = 0; kt < NT; kt += 2) {
    // ---- half A: compute tile kt from buf0; prefetch kt+1 -> buf1 ----
    __syncthreads();  // drains gloads(kt)+scale(kt): in flight for a full phase
    ISSUE(kt + 1, 1);
    LOADS(sclvB, sc0vB, kt + 1);
    TILE_STEP(0, sclvA, sc0vA);
    // ---- half B: compute tile kt+1 from buf1; prefetch kt+2 -> buf0 ----
    __syncthreads();
    if (kt + 2 < NT) {
      ISSUE(kt + 2, 0);
      LOADS(sclvA, sc0vA, kt + 2);
    }
    TILE_STEP(1, sclvB, sc0vB);
  }

  // ---- epilogue ----
  float* ob = out + ((size_t)bh * NS + q0) * ND;
#pragma unroll
  for (int pf = 0; pf < 2; ++pf)
#pragma unroll
    for (int r = 0; r < 4; ++r) {
      float lv = __shfl(ls_[pf], quad * 4 + r);
      float inv = 1.0f / lv;
      int row = pf * 16 + quad * 4 + r;
#pragma unroll
      for (int n0 = 0; n0 < 8; ++n0)
        ob[(size_t)row * ND + n0 * 16 + c] = O[pf][n0][r] * inv;
    }
}

// ---------------- fallback (R1 fp32 kernel, verified) ----------------
#define TQ 16
#define TK 64
#define PITCH 129
__launch_bounds__(256, 2)
__global__ void attn_fp32(const float* __restrict__ Q, const float* __restrict__ K,
                          const float* __restrict__ V, const float* __restrict__ scale,
                          float* __restrict__ out) {
  __shared__ float qs[TQ][ND];
  __shared__ float kv[TK][PITCH];
  __shared__ float ps[4][4][TK];
  const int tid = threadIdx.x;
  const int w = tid >> 6, l = tid & 63;
  const int bid = blockIdx.x;
  const int qt = bid & 63, h = (bid >> 6) & 15, b = bid >> 10;
  const size_t bh = (size_t)b * NH + h;
  const float* Qb = Q + (bh * NS + (size_t)qt * TQ) * ND;
  const float* Kb = K + bh * NS * ND;
  const float* Vb = V + bh * NS * ND;
  {
    const float4* Q4 = (const float4*)Qb;
    float4* qs4 = (float4*)&qs[0][0];
    qs4[tid] = Q4[tid];
    qs4[tid + 256] = Q4[tid + 256];
  }
  const int q0 = qt * TQ + w * 4;
  const float* sc0p[4];
  const float* sclp[4];
#pragma unroll
  for (int i = 0; i < 4; ++i) {
    const int qg = q0 + i;
    sc0p[i] = scale + ((size_t)h * NS + qg) * NS;
    sclp[i] = scale + (bh * NS + qg) * NS;
  }
  float m[4] = {-INFINITY, -INFINITY, -INFINITY, -INFINITY};
  float lsum[4] = {0.f, 0.f, 0.f, 0.f};
  float oa[4] = {0.f, 0.f, 0.f, 0.f};
  float ob[4] = {0.f, 0.f, 0.f, 0.f};
  for (int kt = 0; kt < NS / TK; ++kt) {
    __syncthreads();
    {
      const float4* K4 = (const float4*)(Kb + (size_t)kt * TK * ND);
#pragma unroll
      for (int i = 0; i < 8; ++i) {
        const int f = tid + i * 256;
        const float4 t4 = K4[f];
        const int r = f >> 5, cc = (f & 31) << 2;
        kv[r][cc] = t4.x; kv[r][cc + 1] = t4.y; kv[r][cc + 2] = t4.z; kv[r][cc + 3] = t4.w;
      }
    }
    __syncthreads();
    const int kg = kt * TK + l;
    float sc0[4], scl[4];
#pragma unroll
    for (int i = 0; i < 4; ++i) { sc0[i] = sc0p[i][kg]; scl[i] = sclp[i][kg]; }
    float s[4] = {0.f, 0.f, 0.f, 0.f};
#pragma unroll 8
    for (int d = 0; d < ND; ++d) {
      const float kd = kv[l][d];
      s[0] = fmaf(qs[w * 4 + 0][d], kd, s[0]);
      s[1] = fmaf(qs[w * 4 + 1][d], kd, s[1]);
      s[2] = fmaf(qs[w * 4 + 2][d], kd, s[2]);
      s[3] = fmaf(qs[w * 4 + 3][d], kd, s[3]);
    }
#pragma unroll
    for (int i = 0; i < 4; ++i) {
      const float svv = s[i] * scl[i] * rsqrtf(sc0[i]);
      float mx = svv;
#pragma unroll
      for (int off = 32; off > 0; off >>= 1) mx = fmaxf(mx, __shfl_xor(mx, off));
      const float mn = fmaxf(m[i], mx);
      const float p = __expf(svv - mn);
      const float al = __expf(m[i] - mn);
      float psum = p;
#pragma unroll
      for (int off = 32; off > 0; off >>= 1) psum += __shfl_xor(psum, off);
      lsum[i] = lsum[i] * al + psum;
      m[i] = mn;
      oa[i] *= al;
      ob[i] *= al;
      ps[w][i][l] = p;
    }
    __syncthreads();
    {
      const float4* V4 = (const float4*)(Vb + (size_t)kt * TK * ND);
#pragma unroll
      for (int i = 0; i < 8; ++i) {
        const int f = tid + i * 256;
        const float4 t4 = V4[f];
        const int r = f >> 5, cc = (f & 31) << 2;
        kv[r][cc] = t4.x; kv[r][cc + 1] = t4.y; kv[r][cc + 2] = t4.z; kv[r][cc + 3] = t4.w;
      }
    }
    __syncthreads();
#pragma unroll 4
    for (int k2 = 0; k2 < TK; ++k2) {
      const float v0 = kv[k2][l];
      const float v1 = kv[k2][64 + l];
#pragma unroll
      for (int i = 0; i < 4; ++i) {
        const float p = ps[w][i][k2];
        oa[i] = fmaf(p, v0, oa[i]);
        ob[i] = fmaf(p, v1, ob[i]);
      }
    }
  }
  float* op = out + (bh * NS + q0) * ND;
#pragma unroll
  for (int i = 0; i < 4; ++i) {
    const float inv = 1.0f / lsum[i];
    op[(size_t)i * ND + l] = oa[i] * inv;
    op[(size_t)i * ND + 64 + l] = ob[i] * inv;
  }
}

extern "C" void kernel_launch(void* const* d_in, const int* in_sizes, int n_in,
                              void* d_out, int out_size, void* d_ws, size_t ws_size,
                              hipStream_t stream) {
  const float* Q = (const float*)d_in[0];
  const float* K = (const float*)d_in[1];
  const float* V = (const float*)d_in[2];
  const float* scale = (const float*)d_in[3];
  float* out = (float*)d_out;

  const size_t KV_BYTES = (size_t)NB * NH * NS * ND * 2;  // 32 MiB each
  const size_t needB = 2 * KV_BYTES;                      // 64 MiB

  if (ws_size >= needB) {
    short* Kimg = (short*)d_ws;
    short* Vimg = (short*)((char*)d_ws + KV_BYTES);
    prep_kv<<<dim3(8192), dim3(256), 0, stream>>>(K, Kimg, V, Vimg);
    attn_f16<<<dim3(1024), dim3(256), 0, stream>>>(Q, Kimg, Vimg, scale, out);
  } else {
    attn_fp32<<<dim3(NB * NH * (NS / TK) * 4), dim3(256), 0, stream>>>(Q, K, V, scale,
                                                                       out);
  }
}